// Round 18
// baseline (190.361 us; speedup 1.0000x reference)
//
#include <hip/hip_runtime.h>
#include <hip/hip_bf16.h>
#include <stdint.h>

typedef __attribute__((ext_vector_type(4))) float f32x4;
typedef __attribute__((ext_vector_type(8))) short short8;

#define B_   32
#define L_   512
#define DE_  512
#define S_   32
#define ED_  128
#define AD_  256
#define HD_  512
#define VOC_ 32000
#define M_   1024
#define SCL_ 2.885390081777927f   // 2*log2(e): tanh(z) = 1 - 2/(2^(SCL*z)+1)

__device__ __forceinline__ unsigned short f2bf(float f){
  union { float f; unsigned int u; } v; v.f = f;
  unsigned int u = v.u;
  unsigned int r = (u + 0x7FFFu + ((u >> 16) & 1u)) >> 16;  // RNE
  return (unsigned short)r;
}

__device__ __forceinline__ float bf2f(unsigned short u){
  union { unsigned int u; float f; } v; v.u = ((unsigned int)u) << 16;
  return v.f;
}

// raw v_exp_f32 (2^x) — avoids libm exp2f's fixup sequence
__device__ __forceinline__ float hw_exp2(float x){
#if __has_builtin(__builtin_amdgcn_exp2f)
  return __builtin_amdgcn_exp2f(x);
#else
  float r;
  asm("v_exp_f32 %0, %1" : "=v"(r) : "v"(x));
  return r;
#endif
}

__device__ __forceinline__ void gl_lds16(const void* g, void* l){
  __builtin_amdgcn_global_load_lds(
      (const __attribute__((address_space(1))) unsigned int*)g,
      (__attribute__((address_space(3))) unsigned int*)l, 16, 0, 0);
}

// ---------------- fused prologue: enc cvt (8192 blk) + eW cvt (128 blk) + small (96 blk) ----
extern "C" __global__ void __launch_bounds__(256)
k_prep(const float* __restrict__ enc, unsigned short* __restrict__ enc_bf,
       const float* __restrict__ eW, unsigned short* __restrict__ encW_bf,
       const float* __restrict__ pos,
       const float* __restrict__ dW, const float* __restrict__ db,
       const float* __restrict__ hW, const float* __restrict__ hb,
       float* __restrict__ dq, unsigned short* __restrict__ hbf){
  int blk = blockIdx.x, tid = threadIdx.x;
  if (blk < 8192){                       // enc: 2,097,152 f32x4, one per thread
    int i = blk * 256 + tid;
    f32x4 v = ((const f32x4*)enc)[i];
    ushort4 o;
    o.x = f2bf(v[0]); o.y = f2bf(v[1]); o.z = f2bf(v[2]); o.w = f2bf(v[3]);
    ((ushort4*)enc_bf)[i] = o;
  } else if (blk < 8320){                // eW: 32,768 f32x4
    int i = (blk - 8192) * 256 + tid;
    f32x4 v = ((const f32x4*)eW)[i];
    ushort4 o;
    o.x = f2bf(v[0]); o.y = f2bf(v[1]); o.z = f2bf(v[2]); o.w = f2bf(v[3]);
    ((ushort4*)encW_bf)[i] = o;
  } else {                               // dq [32][256] f32 (pre-scaled), hidden bf16
    int t = (blk - 8320) * 256 + tid;
    if (t < S_ * AD_){
      int s = t >> 8, a = t & 255;
      const float* p = pos + s * ED_;
      const float* wrow = dW + a * ED_;
      float acc = db[a];
      #pragma unroll 4
      for (int e = 0; e < ED_; ++e) acc += p[e] * wrow[e];
      dq[t] = SCL_ * acc;                // pre-scale for exp2-based tanh
    } else if (t < S_ * AD_ + S_ * HD_){
      int u = t - S_ * AD_;
      int s = u >> 9, h = u & 511;
      const float* p = pos + s * ED_;
      const float* wrow = hW + h * ED_;
      float acc = hb[h];
      #pragma unroll 4
      for (int e = 0; e < ED_; ++e) acc += p[e] * wrow[e];
      hbf[u] = f2bf(acc);
    }
  }
}

// ---------------- enc_proj GEMM (128x128 tile, 2-phase dbuf, swizzled LDS):
//   [16384x512]bf16 @ [256x512]bf16^T -> bf16( SCL*(acc+bias) )  [feeds score only]
extern "C" __global__ void __launch_bounds__(256, 4)
k_gemm_encp(const unsigned short* __restrict__ A, const unsigned short* __restrict__ Bt,
            const float* __restrict__ bias, unsigned short* __restrict__ C){
  __shared__ unsigned short As[2][128 * 32];
  __shared__ unsigned short Bs[2][128 * 32];
  int bm = blockIdx.x >> 1, bn = blockIdx.x & 1;
  int tid = threadIdx.x, wid = tid >> 6, lane = tid & 63;
  int fr = lane & 15, fq = lane >> 4;
  int wm = wid >> 1, wn = wid & 1;       // 2x2 waves; wave tile 64x64
  int srow = lane >> 2;
  int scol = ((lane & 3) ^ ((lane >> 3) & 3)) * 8;   // pre-swizzled source col
  int c0 = wid * 2;
  const unsigned short* aS0 = A  + (size_t)(bm * 128 + c0 * 16 + srow) * 512 + scol;
  const unsigned short* aS1 = aS0 + (size_t)16 * 512;
  const unsigned short* bS0 = Bt + (size_t)(bn * 128 + c0 * 16 + srow) * 512 + scol;
  const unsigned short* bS1 = bS0 + (size_t)16 * 512;
  int swzfq = (fq ^ ((fr >> 1) & 3)) * 8;

  f32x4 acc[4][4];
  #pragma unroll
  for (int i = 0; i < 4; ++i)
    #pragma unroll
    for (int j = 0; j < 4; ++j) acc[i][j] = (f32x4)0.0f;

#define STAGE_E(buf, kk) do { \
    gl_lds16(aS0 + (kk), &As[buf][c0 * 512]); \
    gl_lds16(aS1 + (kk), &As[buf][c0 * 512 + 512]); \
    gl_lds16(bS0 + (kk), &Bs[buf][c0 * 512]); \
    gl_lds16(bS1 + (kk), &Bs[buf][c0 * 512 + 512]); \
  } while (0)

  STAGE_E(0, 0);
  __syncthreads();

  int cur = 0;
  for (int t = 0; t < 16; ++t){
    if (t < 15) STAGE_E(cur ^ 1, (size_t)(t + 1) * 32);
    short8 a[4], b[4];
    #pragma unroll
    for (int mf = 0; mf < 4; ++mf) a[mf] = *(const short8*)&As[cur][(wm * 64 + mf * 16 + fr) * 32 + swzfq];
    #pragma unroll
    for (int nf = 0; nf < 4; ++nf) b[nf] = *(const short8*)&Bs[cur][(wn * 64 + nf * 16 + fr) * 32 + swzfq];
    #pragma unroll
    for (int mf = 0; mf < 4; ++mf)
      #pragma unroll
      for (int nf = 0; nf < 4; ++nf)
        acc[mf][nf] = __builtin_amdgcn_mfma_f32_16x16x32_bf16(a[mf], b[nf], acc[mf][nf], 0, 0, 0);
    __syncthreads();
    cur ^= 1;
  }
#undef STAGE_E

  #pragma unroll
  for (int mf = 0; mf < 4; ++mf){
    int row = bm * 128 + wm * 64 + mf * 16 + fq * 4;
    #pragma unroll
    for (int nf = 0; nf < 4; ++nf){
      int col = bn * 128 + wn * 64 + nf * 16 + fr;
      float bv = bias[col];
      #pragma unroll
      for (int j = 0; j < 4; ++j)
        C[(size_t)(row + j) * 256 + col] = f2bf(SCL_ * (acc[mf][nf][j] + bv));
    }
  }
}

// ---------------- fused middle (512-thread blocks):
//   wprep (blocks 0-249, 128 fcW rows each) || attn scores (blocks 250-1273)
// score thread = (s, g16): 32 pinned VGPRs; hw_exp2 = bare v_exp_f32.
extern "C" __global__ void __launch_bounds__(512)
k_mid(const float* __restrict__ fcW, const unsigned short* __restrict__ hbf,
      const float* __restrict__ fcb, unsigned short* __restrict__ Wc,
      float* __restrict__ logh,
      const unsigned short* __restrict__ encp, const float* __restrict__ dq,
      const float* __restrict__ vW, float* __restrict__ scoreT){
  __shared__ char smem[40960];           // score: eL 8 KB + pp 32 KB
  int blk = blockIdx.x, tid = threadIdx.x;
  if (blk < 250){
    // ---------------- wprep: Wc_bf convert + logh for 128 fcW rows ----------------
    int base = blk * 128;
    int wid = tid >> 6, lane = tid & 63;
    int fr = lane & 15, fq = lane >> 4;
    // part 1: convert upper half (cols 512:1024) of 128 rows: 16384 f32x4
    #pragma unroll 8
    for (int i = 0; i < 32; ++i){
      int idx = i * 512 + tid;
      int row = idx >> 7, c4 = idx & 127;
      f32x4 v = *(const f32x4*)&fcW[(size_t)(base + row) * 1024 + 512 + c4 * 4];
      ushort4 o;
      o.x = f2bf(v[0]); o.y = f2bf(v[1]); o.z = f2bf(v[2]); o.w = f2bf(v[3]);
      *(ushort4*)&Wc[(size_t)(base + row) * 512 + c4 * 4] = o;
    }
    // part 2: logh for 128 cols (8 waves x 16 cols), LDS-free bf16 MFMA vs hbf
    int col = base + wid * 16 + fr;
    const float* brow = fcW + (size_t)col * 1024;
    f32x4 acc0 = (f32x4)0.0f, acc1 = (f32x4)0.0f;
    #pragma unroll 4
    for (int k0 = 0; k0 < 512; k0 += 32){
      int ko = k0 + fq * 8;
      f32x4 b0 = *(const f32x4*)(brow + ko);
      f32x4 b1 = *(const f32x4*)(brow + ko + 4);
      short8 bfr;
      bfr[0] = (short)f2bf(b0[0]); bfr[1] = (short)f2bf(b0[1]);
      bfr[2] = (short)f2bf(b0[2]); bfr[3] = (short)f2bf(b0[3]);
      bfr[4] = (short)f2bf(b1[0]); bfr[5] = (short)f2bf(b1[1]);
      bfr[6] = (short)f2bf(b1[2]); bfr[7] = (short)f2bf(b1[3]);
      short8 a0 = *(const short8*)&hbf[(size_t)fr * 512 + ko];
      short8 a1 = *(const short8*)&hbf[(size_t)(16 + fr) * 512 + ko];
      acc0 = __builtin_amdgcn_mfma_f32_16x16x32_bf16(a0, bfr, acc0, 0, 0, 0);
      acc1 = __builtin_amdgcn_mfma_f32_16x16x32_bf16(a1, bfr, acc1, 0, 0, 0);
    }
    float bv = fcb[col];
    #pragma unroll
    for (int j = 0; j < 4; ++j){
      logh[(size_t)(fq * 4 + j) * VOC_ + col]      = acc0[j] + bv;
      logh[(size_t)(16 + fq * 4 + j) * VOC_ + col] = acc1[j] + bv;
    }
  } else {
    // ---------------- attn scores: block (b, c) owns 16 l-rows, all 32 s ----------
    // LDS slot layout per row: slot sl<16 holds global 16B-group 2*sl, else 2*(sl-16)+1
    // -> thread g reads slots g and g+16 (banks 4g%32: 2-way, free).
    unsigned short* eL = (unsigned short*)smem;       // [16 rows][256] bf16 = 8 KB
    float* pp = (float*)(smem + 8192);                // [16 l][512] f32 = 32 KB
    int blk2 = blk - 250;                             // 1024 = 32 b x 32 chunks
    int b = blk2 >> 5, c = blk2 & 31;
    int w = tid >> 6, lane = tid & 63;
    {
      int sl = lane & 31;
      int row = 2 * w + (lane >> 5);
      int srcgrp = (sl < 16) ? (2 * sl) : (2 * (sl - 16) + 1);
      gl_lds16(encp + (size_t)(b * 512 + c * 16 + row) * 256 + srcgrp * 8,
               &eL[w * 512]);                         // wave-uniform base, lane*16B
    }
    int s = tid >> 4, g = tid & 15;                   // 32 s x 16 g
    f32x4 dqv[4], vv[4];
    #pragma unroll
    for (int k = 0; k < 4; ++k){
      dqv[k] = *(const f32x4*)&dq[s * 256 + g * 16 + k * 4];
      vv[k]  = *(const f32x4*)&vW[g * 16 + k * 4];
    }
    float Vg = 0.0f;
    #pragma unroll
    for (int k = 0; k < 4; ++k)
      Vg += (vv[k][0] + vv[k][1]) + (vv[k][2] + vv[k][3]);
    __syncthreads();   // eL ready
    #pragma unroll 2
    for (int l = 0; l < 16; ++l){
      short8 ea = *(const short8*)&eL[l * 256 + g * 8];          // elems [16g,16g+8)
      short8 eb = *(const short8*)&eL[l * 256 + (g + 16) * 8];   // elems [16g+8,16g+16)
      const unsigned int* ua = (const unsigned int*)&ea;
      const unsigned int* ub = (const unsigned int*)&eb;
      float a0 = 0, a1 = 0, a2 = 0, a3 = 0;    // 4 independent chains
      #pragma unroll
      for (int j = 0; j < 2; ++j){             // ea: dqv[0..1], vv[0..1]
        unsigned int w0 = ua[j * 2], w1 = ua[j * 2 + 1];
        float t0 = hw_exp2(__uint_as_float(w0 << 16)         + dqv[j][0]);
        float t1 = hw_exp2(__uint_as_float(w0 & 0xffff0000u) + dqv[j][1]);
        float t2 = hw_exp2(__uint_as_float(w1 << 16)         + dqv[j][2]);
        float t3 = hw_exp2(__uint_as_float(w1 & 0xffff0000u) + dqv[j][3]);
        a0 = fmaf(vv[j][0], __builtin_amdgcn_rcpf(t0 + 1.0f), a0);
        a1 = fmaf(vv[j][1], __builtin_amdgcn_rcpf(t1 + 1.0f), a1);
        a2 = fmaf(vv[j][2], __builtin_amdgcn_rcpf(t2 + 1.0f), a2);
        a3 = fmaf(vv[j][3], __builtin_amdgcn_rcpf(t3 + 1.0f), a3);
      }
      #pragma unroll
      for (int j = 0; j < 2; ++j){             // eb: dqv[2..3], vv[2..3]
        unsigned int w0 = ub[j * 2], w1 = ub[j * 2 + 1];
        float t0 = hw_exp2(__uint_as_float(w0 << 16)         + dqv[2 + j][0]);
        float t1 = hw_exp2(__uint_as_float(w0 & 0xffff0000u) + dqv[2 + j][1]);
        float t2 = hw_exp2(__uint_as_float(w1 << 16)         + dqv[2 + j][2]);
        float t3 = hw_exp2(__uint_as_float(w1 & 0xffff0000u) + dqv[2 + j][3]);
        a0 = fmaf(vv[2 + j][0], __builtin_amdgcn_rcpf(t0 + 1.0f), a0);
        a1 = fmaf(vv[2 + j][1], __builtin_amdgcn_rcpf(t1 + 1.0f), a1);
        a2 = fmaf(vv[2 + j][2], __builtin_amdgcn_rcpf(t2 + 1.0f), a2);
        a3 = fmaf(vv[2 + j][3], __builtin_amdgcn_rcpf(t3 + 1.0f), a3);
      }
      pp[l * 512 + tid] = fmaf(-2.0f, (a0 + a1) + (a2 + a3), Vg);
    }
    __syncthreads();
    // reduce 16 g-partials per (l,s); write scoreT [b][l][s]
    {
      int l = tid >> 5, ss = tid & 31;
      const float* p = &pp[l * 512 + ss * 16];
      f32x4 x0 = *(const f32x4*)(p);
      f32x4 x1 = *(const f32x4*)(p + 4);
      f32x4 x2 = *(const f32x4*)(p + 8);
      f32x4 x3 = *(const f32x4*)(p + 12);
      float sum = ((x0[0] + x0[1]) + (x0[2] + x0[3])) + ((x1[0] + x1[1]) + (x1[2] + x1[3]))
                + ((x2[0] + x2[1]) + (x2[2] + x2[3])) + ((x3[0] + x3[1]) + (x3[2] + x3[3]));
      scoreT[((size_t)b * 512 + c * 16 + l) * 32 + ss] = sum;
    }
  }
}

// ---------------- context (softmax folded in):
//   stage scoreT[b] -> LDS (XOR-swizzled), per-s softmax in place, then
//   ctx[b*32+s][d] = sum_l w[b,s,l] * enc_bf[b,l,d] -> bf16
extern "C" __global__ void __launch_bounds__(256)
k_ctx(const unsigned short* __restrict__ encb, const float* __restrict__ scoreT,
      unsigned short* __restrict__ ctx){
  __shared__ float wl[32 * 512];        // 64 KB, [s][l ^ s] swizzle
  __shared__ float pm[32][8], ps[32][8];
  __shared__ float Mf[32], invf[32];
  int b = blockIdx.x >> 4, dt = blockIdx.x & 15;
  int tid = threadIdx.x;
  for (int idx = tid; idx < 16384; idx += 256){
    int l = idx >> 5, s = idx & 31;
    wl[s * 512 + (l ^ s)] = scoreT[(size_t)b * 16384 + idx];
  }
  __syncthreads();
  int s2 = tid & 31, part = tid >> 5;
  float m = -1e30f;
  for (int l = part * 64; l < part * 64 + 64; ++l)
    m = fmaxf(m, wl[s2 * 512 + (l ^ s2)]);
  pm[s2][part] = m;
  __syncthreads();
  float M = pm[s2][0];
  #pragma unroll
  for (int j = 1; j < 8; ++j) M = fmaxf(M, pm[s2][j]);
  float sum = 0.0f;
  for (int l = part * 64; l < part * 64 + 64; ++l)
    sum += __expf(wl[s2 * 512 + (l ^ s2)] - M);
  ps[s2][part] = sum;
  __syncthreads();
  if (part == 0){
    float Lt = ps[s2][0];
    #pragma unroll
    for (int j = 1; j < 8; ++j) Lt += ps[s2][j];
    Mf[s2] = M;
    invf[s2] = __builtin_amdgcn_rcpf(Lt);
  }
  __syncthreads();
  for (int l = part * 64; l < part * 64 + 64; ++l){
    int a = s2 * 512 + (l ^ s2);
    wl[a] = __expf(wl[a] - Mf[s2]) * invf[s2];
  }
  __syncthreads();
  int d = dt * 32 + (tid & 31);
  int grp = tid >> 5;
  int r0 = grp * 4, r1 = r0 + 1, r2 = r0 + 2, r3 = r0 + 3;
  float acc0 = 0, acc1 = 0, acc2 = 0, acc3 = 0;
  const unsigned short* ebase = encb + (size_t)b * 262144 + d;   // 512*512
  #pragma unroll 8
  for (int l = 0; l < 512; ++l){
    float e = bf2f(ebase[(size_t)l * 512]);
    acc0 = fmaf(wl[r0 * 512 + (l ^ r0)], e, acc0);
    acc1 = fmaf(wl[r1 * 512 + (l ^ r1)], e, acc1);
    acc2 = fmaf(wl[r2 * 512 + (l ^ r2)], e, acc2);
    acc3 = fmaf(wl[r3 * 512 + (l ^ r3)], e, acc3);
  }
  size_t obase = (size_t)(b * 32 + r0) * 512 + d;
  ctx[obase]        = f2bf(acc0);
  ctx[obase + 512]  = f2bf(acc1);
  ctx[obase + 1024] = f2bf(acc2);
  ctx[obase + 1536] = f2bf(acc3);
}

// ---------------- main GEMM (128x128 tile, wave 64x64, A-dbuf + B-3buf, vmcnt(2)):
//   out[m][v] = ctx[m] . Wc[v] + logh[m&31][v]
//   40 KB LDS -> 4 blocks/CU; 2000 blocks for cross-block write/compute overlap.
extern "C" __global__ void __launch_bounds__(256, 4)
k_gemm_main(const unsigned short* __restrict__ Abf, const unsigned short* __restrict__ Wc,
            const float* __restrict__ logh, float* __restrict__ out){
  __shared__ char smem[40960];
  unsigned short* As0 = (unsigned short*)smem;            // 2 x 128*32 bf16 = 16 KB
  unsigned short* Bs0 = (unsigned short*)(smem + 16384);  // 3 x 128*32 bf16 = 24 KB
  float* ep = (float*)smem;                               // epilogue scratch (reused)
  int orig = blockIdx.x;
  int wg = (orig & 7) * 250 + (orig >> 3);   // bijective: 2000 % 8 == 0
  int bm = wg & 7, bn = wg >> 3;             // bm<8 (1024/128), bn<250 (32000/128)
  int tid = threadIdx.x, wid = tid >> 6, lane = tid & 63;
  int fr = lane & 15, fq = lane >> 4;
  int wm = wid >> 1, wn = wid & 1;           // 2x2 waves; wave tile 64x64
  int abase = bm * 128, bbase = bn * 128;
  int srow = lane >> 2;
  int scol = ((lane & 3) ^ ((lane >> 3) & 3)) * 8;
  const unsigned short* aS0 = Abf + (size_t)(abase + wid * 32 + srow) * 512 + scol;
  const unsigned short* aS1 = aS0 + (size_t)16 * 512;
  const unsigned short* bS0 = Wc  + (size_t)(bbase + wid * 32 + srow) * 512 + scol;
  const unsigned short* bS1 = bS0 + (size_t)16 * 512;
  int swzfq = (fq ^ ((fr >> 1) & 3)) * 8;

  f32x4 acc[4][4];
  #pragma unroll
  for (int i = 0; i < 4; ++i)
    #pragma unroll
    for (int jj = 0; jj < 4; ++jj) acc[i][jj] = (f32x4)0.0f;

#define STAGE_A(buf, kk) do { \
    gl_lds16(aS0 + (kk), As0 + (buf) * 4096 + wid * 1024); \
    gl_lds16(aS1 + (kk), As0 + (buf) * 4096 + wid * 1024 + 512); \
  } while (0)
#define STAGE_B(buf, kk) do { \
    gl_lds16(bS0 + (kk), Bs0 + (buf) * 4096 + wid * 1024); \
    gl_lds16(bS1 + (kk), Bs0 + (buf) * 4096 + wid * 1024 + 512); \
  } while (0)

  STAGE_A(0, 0);
  STAGE_B(0, 0);
  STAGE_B(1, 32);
  asm volatile("s_waitcnt vmcnt(2)" ::: "memory");   // A0,B0 landed; B1 (2 loads) flying
  __builtin_amdgcn_s_barrier();
  __builtin_amdgcn_sched_barrier(0);

  #pragma unroll
  for (int t = 0; t < 16; ++t){
    const int ca = t & 1, cb = t % 3;
    short8 a[4], b[4];
    // ---- phase 0: stage A(t+1); compute mf0-1 ----
    if (t < 15) STAGE_A(ca ^ 1, (size_t)(t + 1) * 32);
    #pragma unroll
    for (int nf = 0; nf < 4; ++nf)
      b[nf] = *(const short8*)&Bs0[cb * 4096 + (wn * 64 + nf * 16 + fr) * 32 + swzfq];
    #pragma unroll
    for (int mf = 0; mf < 2; ++mf)
      a[mf] = *(const short8*)&As0[ca * 4096 + (wm * 64 + mf * 16 + fr) * 32 + swzfq];
    __builtin_amdgcn_s_setprio(1);
    #pragma unroll
    for (int mf = 0; mf < 2; ++mf)
      #pragma unroll
      for (int nf = 0; nf < 4; ++nf)
        acc[mf][nf] = __builtin_amdgcn_mfma_f32_16x16x32_bf16(a[mf], b[nf], acc[mf][nf], 0, 0, 0);
    __builtin_amdgcn_s_setprio(0);
    // ---- phase 1: stage B(t+2); compute mf2-3 ----
    if (t < 14) STAGE_B((t + 2) % 3, (size_t)(t + 2) * 32);
    #pragma unroll
    for (int mf = 2; mf < 4; ++mf)
      a[mf] = *(const short8*)&As0[ca * 4096 + (wm * 64 + mf * 16 + fr) * 32 + swzfq];
    __builtin_amdgcn_s_setprio(1);
    #pragma unroll
    for (int mf = 2; mf < 4; ++mf)
      #pragma unroll
      for (int nf = 0; nf < 4; ++nf)
        acc[mf][nf] = __builtin_amdgcn_mfma_f32_16x16x32_bf16(a[mf], b[nf], acc[mf][nf], 0, 0, 0);
    __builtin_amdgcn_s_setprio(0);
    // ---- boundary: A(t+1),B(t+1) landed; B(t+2)'s 2 loads may fly ----
    if (t < 14)       asm volatile("s_waitcnt vmcnt(2)" ::: "memory");
    else if (t == 14) asm volatile("s_waitcnt vmcnt(0)" ::: "memory");
    if (t < 15){
      __builtin_amdgcn_s_barrier();
      __builtin_amdgcn_sched_barrier(0);
    }
  }
#undef STAGE_A
#undef STAGE_B

  // ---- epilogue: add logh, transpose via per-wave LDS, store dwordx4 ----
  __syncthreads();                          // all waves done reading As0/Bs0
  float* myep = ep + wid * 1088;            // 16 rows x 68 f32 (pad) = 4352 B/wave
  int colb = bn * 128 + wn * 64;
  #pragma unroll
  for (int mf = 0; mf < 4; ++mf){
    // write phase: final = acc + logh  ->  ep[row16][col64]
    #pragma unroll
    for (int nf = 0; nf < 4; ++nf){
      int col = colb + nf * 16 + fr;
      #pragma unroll
      for (int jj = 0; jj < 4; ++jj){
        int lrow = (mf * 16 + fq * 4 + jj) & 31;   // logh row (bm*128,wm*64 are mult of 32)
        myep[(fq * 4 + jj) * 68 + nf * 16 + fr] = acc[mf][nf][jj] + logh[(size_t)lrow * VOC_ + col];
      }
    }
    asm volatile("s_waitcnt lgkmcnt(0)" ::: "memory");
    __builtin_amdgcn_sched_barrier(0);
    // read phase: lane holds 4 consecutive cols -> dwordx4 stores (256B/row/instr)
    int rrow = lane >> 4;                    // 0..3
    int rcol = (lane & 15) * 4;              // 0..60
    #pragma unroll
    for (int cch = 0; cch < 4; ++cch){
      f32x4 v = *(const f32x4*)&myep[(rrow + 4 * cch) * 68 + rcol];
      int gr = bm * 128 + wm * 64 + mf * 16 + rrow + 4 * cch;
      *(f32x4*)&out[(size_t)gr * VOC_ + colb + rcol] = v;
    }
    asm volatile("s_waitcnt lgkmcnt(0)" ::: "memory");
    __builtin_amdgcn_sched_barrier(0);
  }
}

extern "C" void kernel_launch(void* const* d_in, const int* in_sizes, int n_in,
                              void* d_out, int out_size, void* d_ws, size_t ws_size,
                              hipStream_t stream){
  const float* enc = (const float*)d_in[0];
  // d_in[1] = target_seq (unused: only its shape matters in the reference)
  const float* pos = (const float*)d_in[2];
  const float* dW  = (const float*)d_in[3];
  const float* db  = (const float*)d_in[4];
  const float* eW  = (const float*)d_in[5];
  const float* eb  = (const float*)d_in[6];
  const float* vW  = (const float*)d_in[7];
  // d_in[8] = attn_score_b: constant over l, cancels exactly in softmax
  const float* hW  = (const float*)d_in[9];
  const float* hb  = (const float*)d_in[10];
  const float* fcW = (const float*)d_in[11];
  const float* fcb = (const float*)d_in[12];
  float* out = (float*)d_out;

  char* w = (char*)d_ws;
  unsigned short* Wc_bf   = (unsigned short*)(w);               // 32,768,000 B
  unsigned short* enc_bf  = (unsigned short*)(w + 32768000);    // 16,777,216 B
  unsigned short* encp_bf = (unsigned short*)(w + 49545216);    //  8,388,608 B
  unsigned short* ctx     = (unsigned short*)(w + 57933824);    //  1,048,576 B
  float*          logh    = (float*)(w + 58982400);             //  4,096,000 B
  float*          dq      = (float*)(w + 63078400);             //     32,768 B
  unsigned short* hbf     = (unsigned short*)(w + 63111168);    //     32,768 B
  unsigned short* encW_bf = (unsigned short*)(w + 63143936);    //    262,144 B
  float*          scoreT  = (float*)(w + 63406080);             //  2,097,152 B (total ~65.5 MB)

  k_prep<<<dim3(8416), dim3(256), 0, stream>>>(enc, enc_bf, eW, encW_bf,
                                               pos, dW, db, hW, hb, dq, hbf);
  k_gemm_encp<<<dim3(256), dim3(256), 0, stream>>>(enc_bf, encW_bf, eb, encp_bf);
  k_mid<<<dim3(1274), dim3(512), 0, stream>>>(fcW, hbf, fcb, Wc_bf, logh,
                                              encp_bf, dq, vW, scoreT);
  k_ctx<<<dim3(512), dim3(256), 0, stream>>>(enc_bf, scoreT, ctx);
  k_gemm_main<<<dim3(2000), dim3(256), 0, stream>>>(ctx, Wc_bf, logh, out);
}

// Round 19
// 186.052 us; speedup vs baseline: 1.0232x; 1.0232x over previous
//
#include <hip/hip_runtime.h>
#include <hip/hip_bf16.h>
#include <stdint.h>

typedef __attribute__((ext_vector_type(4))) float f32x4;
typedef __attribute__((ext_vector_type(8))) short short8;

#define B_   32
#define L_   512
#define DE_  512
#define S_   32
#define ED_  128
#define AD_  256
#define HD_  512
#define VOC_ 32000
#define M_   1024
#define SCL_ 2.885390081777927f   // 2*log2(e): tanh(z) = 1 - 2/(2^(SCL*z)+1)

__device__ __forceinline__ unsigned short f2bf(float f){
  union { float f; unsigned int u; } v; v.f = f;
  unsigned int u = v.u;
  unsigned int r = (u + 0x7FFFu + ((u >> 16) & 1u)) >> 16;  // RNE
  return (unsigned short)r;
}

__device__ __forceinline__ float bf2f(unsigned short u){
  union { unsigned int u; float f; } v; v.u = ((unsigned int)u) << 16;
  return v.f;
}

// raw v_exp_f32 (2^x) — avoids libm exp2f's fixup sequence
__device__ __forceinline__ float hw_exp2(float x){
#if __has_builtin(__builtin_amdgcn_exp2f)
  return __builtin_amdgcn_exp2f(x);
#else
  float r;
  asm("v_exp_f32 %0, %1" : "=v"(r) : "v"(x));
  return r;
#endif
}

__device__ __forceinline__ void gl_lds16(const void* g, void* l){
  __builtin_amdgcn_global_load_lds(
      (const __attribute__((address_space(1))) unsigned int*)g,
      (__attribute__((address_space(3))) unsigned int*)l, 16, 0, 0);
}

// ---------------- fused prologue: enc cvt (8192 blk) + eW cvt (128 blk) + small (96 blk) ----
extern "C" __global__ void __launch_bounds__(256)
k_prep(const float* __restrict__ enc, unsigned short* __restrict__ enc_bf,
       const float* __restrict__ eW, unsigned short* __restrict__ encW_bf,
       const float* __restrict__ pos,
       const float* __restrict__ dW, const float* __restrict__ db,
       const float* __restrict__ hW, const float* __restrict__ hb,
       float* __restrict__ dq, unsigned short* __restrict__ hbf){
  int blk = blockIdx.x, tid = threadIdx.x;
  if (blk < 8192){                       // enc: 2,097,152 f32x4, one per thread
    int i = blk * 256 + tid;
    f32x4 v = ((const f32x4*)enc)[i];
    ushort4 o;
    o.x = f2bf(v[0]); o.y = f2bf(v[1]); o.z = f2bf(v[2]); o.w = f2bf(v[3]);
    ((ushort4*)enc_bf)[i] = o;
  } else if (blk < 8320){                // eW: 32,768 f32x4
    int i = (blk - 8192) * 256 + tid;
    f32x4 v = ((const f32x4*)eW)[i];
    ushort4 o;
    o.x = f2bf(v[0]); o.y = f2bf(v[1]); o.z = f2bf(v[2]); o.w = f2bf(v[3]);
    ((ushort4*)encW_bf)[i] = o;
  } else {                               // dq [32][256] f32 (pre-scaled), hidden bf16
    int t = (blk - 8320) * 256 + tid;
    if (t < S_ * AD_){
      int s = t >> 8, a = t & 255;
      const float* p = pos + s * ED_;
      const float* wrow = dW + a * ED_;
      float acc = db[a];
      #pragma unroll 4
      for (int e = 0; e < ED_; ++e) acc += p[e] * wrow[e];
      dq[t] = SCL_ * acc;                // pre-scale for exp2-based tanh
    } else if (t < S_ * AD_ + S_ * HD_){
      int u = t - S_ * AD_;
      int s = u >> 9, h = u & 511;
      const float* p = pos + s * ED_;
      const float* wrow = hW + h * ED_;
      float acc = hb[h];
      #pragma unroll 4
      for (int e = 0; e < ED_; ++e) acc += p[e] * wrow[e];
      hbf[u] = f2bf(acc);
    }
  }
}

// ---------------- enc_proj GEMM (128x128 tile, 2-phase dbuf, swizzled LDS):
//   [16384x512]bf16 @ [256x512]bf16^T -> bf16( SCL*(acc+bias) )  [feeds score only]
extern "C" __global__ void __launch_bounds__(256, 4)
k_gemm_encp(const unsigned short* __restrict__ A, const unsigned short* __restrict__ Bt,
            const float* __restrict__ bias, unsigned short* __restrict__ C){
  __shared__ unsigned short As[2][128 * 32];
  __shared__ unsigned short Bs[2][128 * 32];
  int bm = blockIdx.x >> 1, bn = blockIdx.x & 1;
  int tid = threadIdx.x, wid = tid >> 6, lane = tid & 63;
  int fr = lane & 15, fq = lane >> 4;
  int wm = wid >> 1, wn = wid & 1;       // 2x2 waves; wave tile 64x64
  int srow = lane >> 2;
  int scol = ((lane & 3) ^ ((lane >> 3) & 3)) * 8;   // pre-swizzled source col
  int c0 = wid * 2;
  const unsigned short* aS0 = A  + (size_t)(bm * 128 + c0 * 16 + srow) * 512 + scol;
  const unsigned short* aS1 = aS0 + (size_t)16 * 512;
  const unsigned short* bS0 = Bt + (size_t)(bn * 128 + c0 * 16 + srow) * 512 + scol;
  const unsigned short* bS1 = bS0 + (size_t)16 * 512;
  int swzfq = (fq ^ ((fr >> 1) & 3)) * 8;

  f32x4 acc[4][4];
  #pragma unroll
  for (int i = 0; i < 4; ++i)
    #pragma unroll
    for (int j = 0; j < 4; ++j) acc[i][j] = (f32x4)0.0f;

#define STAGE_E(buf, kk) do { \
    gl_lds16(aS0 + (kk), &As[buf][c0 * 512]); \
    gl_lds16(aS1 + (kk), &As[buf][c0 * 512 + 512]); \
    gl_lds16(bS0 + (kk), &Bs[buf][c0 * 512]); \
    gl_lds16(bS1 + (kk), &Bs[buf][c0 * 512 + 512]); \
  } while (0)

  STAGE_E(0, 0);
  __syncthreads();

  int cur = 0;
  for (int t = 0; t < 16; ++t){
    if (t < 15) STAGE_E(cur ^ 1, (size_t)(t + 1) * 32);
    short8 a[4], b[4];
    #pragma unroll
    for (int mf = 0; mf < 4; ++mf) a[mf] = *(const short8*)&As[cur][(wm * 64 + mf * 16 + fr) * 32 + swzfq];
    #pragma unroll
    for (int nf = 0; nf < 4; ++nf) b[nf] = *(const short8*)&Bs[cur][(wn * 64 + nf * 16 + fr) * 32 + swzfq];
    #pragma unroll
    for (int mf = 0; mf < 4; ++mf)
      #pragma unroll
      for (int nf = 0; nf < 4; ++nf)
        acc[mf][nf] = __builtin_amdgcn_mfma_f32_16x16x32_bf16(a[mf], b[nf], acc[mf][nf], 0, 0, 0);
    __syncthreads();
    cur ^= 1;
  }
#undef STAGE_E

  #pragma unroll
  for (int mf = 0; mf < 4; ++mf){
    int row = bm * 128 + wm * 64 + mf * 16 + fq * 4;
    #pragma unroll
    for (int nf = 0; nf < 4; ++nf){
      int col = bn * 128 + wn * 64 + nf * 16 + fr;
      float bv = bias[col];
      #pragma unroll
      for (int j = 0; j < 4; ++j)
        C[(size_t)(row + j) * 256 + col] = f2bf(SCL_ * (acc[mf][nf][j] + bv));
    }
  }
}

// ---------------- fused middle (512-thread blocks):
//   wprep (blocks 0-249, 128 fcW rows each) || attn scores (blocks 250-1273)
// score thread = (s, g16): 32 pinned VGPRs; hw_exp2 = bare v_exp_f32.
extern "C" __global__ void __launch_bounds__(512)
k_mid(const float* __restrict__ fcW, const unsigned short* __restrict__ hbf,
      const float* __restrict__ fcb, unsigned short* __restrict__ Wc,
      float* __restrict__ logh,
      const unsigned short* __restrict__ encp, const float* __restrict__ dq,
      const float* __restrict__ vW, float* __restrict__ scoreT){
  __shared__ char smem[40960];           // score: eL 8 KB + pp 32 KB
  int blk = blockIdx.x, tid = threadIdx.x;
  if (blk < 250){
    // ---------------- wprep: Wc_bf convert + logh for 128 fcW rows ----------------
    int base = blk * 128;
    int wid = tid >> 6, lane = tid & 63;
    int fr = lane & 15, fq = lane >> 4;
    // part 1: convert upper half (cols 512:1024) of 128 rows: 16384 f32x4
    #pragma unroll 8
    for (int i = 0; i < 32; ++i){
      int idx = i * 512 + tid;
      int row = idx >> 7, c4 = idx & 127;
      f32x4 v = *(const f32x4*)&fcW[(size_t)(base + row) * 1024 + 512 + c4 * 4];
      ushort4 o;
      o.x = f2bf(v[0]); o.y = f2bf(v[1]); o.z = f2bf(v[2]); o.w = f2bf(v[3]);
      *(ushort4*)&Wc[(size_t)(base + row) * 512 + c4 * 4] = o;
    }
    // part 2: logh for 128 cols (8 waves x 16 cols), LDS-free bf16 MFMA vs hbf
    int col = base + wid * 16 + fr;
    const float* brow = fcW + (size_t)col * 1024;
    f32x4 acc0 = (f32x4)0.0f, acc1 = (f32x4)0.0f;
    #pragma unroll 4
    for (int k0 = 0; k0 < 512; k0 += 32){
      int ko = k0 + fq * 8;
      f32x4 b0 = *(const f32x4*)(brow + ko);
      f32x4 b1 = *(const f32x4*)(brow + ko + 4);
      short8 bfr;
      bfr[0] = (short)f2bf(b0[0]); bfr[1] = (short)f2bf(b0[1]);
      bfr[2] = (short)f2bf(b0[2]); bfr[3] = (short)f2bf(b0[3]);
      bfr[4] = (short)f2bf(b1[0]); bfr[5] = (short)f2bf(b1[1]);
      bfr[6] = (short)f2bf(b1[2]); bfr[7] = (short)f2bf(b1[3]);
      short8 a0 = *(const short8*)&hbf[(size_t)fr * 512 + ko];
      short8 a1 = *(const short8*)&hbf[(size_t)(16 + fr) * 512 + ko];
      acc0 = __builtin_amdgcn_mfma_f32_16x16x32_bf16(a0, bfr, acc0, 0, 0, 0);
      acc1 = __builtin_amdgcn_mfma_f32_16x16x32_bf16(a1, bfr, acc1, 0, 0, 0);
    }
    float bv = fcb[col];
    #pragma unroll
    for (int j = 0; j < 4; ++j){
      logh[(size_t)(fq * 4 + j) * VOC_ + col]      = acc0[j] + bv;
      logh[(size_t)(16 + fq * 4 + j) * VOC_ + col] = acc1[j] + bv;
    }
  } else {
    // ---------------- attn scores: block (b, c) owns 16 l-rows, all 32 s ----------
    // LDS slot layout per row: slot sl<16 holds global 16B-group 2*sl, else 2*(sl-16)+1
    // -> thread g reads slots g and g+16 (banks 4g%32: 2-way, free).
    unsigned short* eL = (unsigned short*)smem;       // [16 rows][256] bf16 = 8 KB
    float* pp = (float*)(smem + 8192);                // [16 l][512] f32 = 32 KB
    int blk2 = blk - 250;                             // 1024 = 32 b x 32 chunks
    int b = blk2 >> 5, c = blk2 & 31;
    int w = tid >> 6, lane = tid & 63;
    {
      int sl = lane & 31;
      int row = 2 * w + (lane >> 5);
      int srcgrp = (sl < 16) ? (2 * sl) : (2 * (sl - 16) + 1);
      gl_lds16(encp + (size_t)(b * 512 + c * 16 + row) * 256 + srcgrp * 8,
               &eL[w * 512]);                         // wave-uniform base, lane*16B
    }
    int s = tid >> 4, g = tid & 15;                   // 32 s x 16 g
    f32x4 dqv[4], vv[4];
    #pragma unroll
    for (int k = 0; k < 4; ++k){
      dqv[k] = *(const f32x4*)&dq[s * 256 + g * 16 + k * 4];
      vv[k]  = *(const f32x4*)&vW[g * 16 + k * 4];
    }
    float Vg = 0.0f;
    #pragma unroll
    for (int k = 0; k < 4; ++k)
      Vg += (vv[k][0] + vv[k][1]) + (vv[k][2] + vv[k][3]);
    __syncthreads();   // eL ready
    #pragma unroll 2
    for (int l = 0; l < 16; ++l){
      short8 ea = *(const short8*)&eL[l * 256 + g * 8];          // elems [16g,16g+8)
      short8 eb = *(const short8*)&eL[l * 256 + (g + 16) * 8];   // elems [16g+8,16g+16)
      const unsigned int* ua = (const unsigned int*)&ea;
      const unsigned int* ub = (const unsigned int*)&eb;
      float a0 = 0, a1 = 0, a2 = 0, a3 = 0;    // 4 independent chains
      #pragma unroll
      for (int j = 0; j < 2; ++j){             // ea: dqv[0..1], vv[0..1]
        unsigned int w0 = ua[j * 2], w1 = ua[j * 2 + 1];
        float t0 = hw_exp2(__uint_as_float(w0 << 16)         + dqv[j][0]);
        float t1 = hw_exp2(__uint_as_float(w0 & 0xffff0000u) + dqv[j][1]);
        float t2 = hw_exp2(__uint_as_float(w1 << 16)         + dqv[j][2]);
        float t3 = hw_exp2(__uint_as_float(w1 & 0xffff0000u) + dqv[j][3]);
        a0 = fmaf(vv[j][0], __builtin_amdgcn_rcpf(t0 + 1.0f), a0);
        a1 = fmaf(vv[j][1], __builtin_amdgcn_rcpf(t1 + 1.0f), a1);
        a2 = fmaf(vv[j][2], __builtin_amdgcn_rcpf(t2 + 1.0f), a2);
        a3 = fmaf(vv[j][3], __builtin_amdgcn_rcpf(t3 + 1.0f), a3);
      }
      #pragma unroll
      for (int j = 0; j < 2; ++j){             // eb: dqv[2..3], vv[2..3]
        unsigned int w0 = ub[j * 2], w1 = ub[j * 2 + 1];
        float t0 = hw_exp2(__uint_as_float(w0 << 16)         + dqv[2 + j][0]);
        float t1 = hw_exp2(__uint_as_float(w0 & 0xffff0000u) + dqv[2 + j][1]);
        float t2 = hw_exp2(__uint_as_float(w1 << 16)         + dqv[2 + j][2]);
        float t3 = hw_exp2(__uint_as_float(w1 & 0xffff0000u) + dqv[2 + j][3]);
        a0 = fmaf(vv[2 + j][0], __builtin_amdgcn_rcpf(t0 + 1.0f), a0);
        a1 = fmaf(vv[2 + j][1], __builtin_amdgcn_rcpf(t1 + 1.0f), a1);
        a2 = fmaf(vv[2 + j][2], __builtin_amdgcn_rcpf(t2 + 1.0f), a2);
        a3 = fmaf(vv[2 + j][3], __builtin_amdgcn_rcpf(t3 + 1.0f), a3);
      }
      pp[l * 512 + tid] = fmaf(-2.0f, (a0 + a1) + (a2 + a3), Vg);
    }
    __syncthreads();
    // reduce 16 g-partials per (l,s); write scoreT [b][l][s]
    {
      int l = tid >> 5, ss = tid & 31;
      const float* p = &pp[l * 512 + ss * 16];
      f32x4 x0 = *(const f32x4*)(p);
      f32x4 x1 = *(const f32x4*)(p + 4);
      f32x4 x2 = *(const f32x4*)(p + 8);
      f32x4 x3 = *(const f32x4*)(p + 12);
      float sum = ((x0[0] + x0[1]) + (x0[2] + x0[3])) + ((x1[0] + x1[1]) + (x1[2] + x1[3]))
                + ((x2[0] + x2[1]) + (x2[2] + x2[3])) + ((x3[0] + x3[1]) + (x3[2] + x3[3]));
      scoreT[((size_t)b * 512 + c * 16 + l) * 32 + ss] = sum;
    }
  }
}

// ---------------- context (softmax folded in):
//   stage scoreT[b] -> LDS (XOR-swizzled), per-s softmax in place, then
//   ctx[b*32+s][d] = sum_l w[b,s,l] * enc_bf[b,l,d] -> bf16
extern "C" __global__ void __launch_bounds__(256)
k_ctx(const unsigned short* __restrict__ encb, const float* __restrict__ scoreT,
      unsigned short* __restrict__ ctx){
  __shared__ float wl[32 * 512];        // 64 KB, [s][l ^ s] swizzle
  __shared__ float pm[32][8], ps[32][8];
  __shared__ float Mf[32], invf[32];
  int b = blockIdx.x >> 4, dt = blockIdx.x & 15;
  int tid = threadIdx.x;
  for (int idx = tid; idx < 16384; idx += 256){
    int l = idx >> 5, s = idx & 31;
    wl[s * 512 + (l ^ s)] = scoreT[(size_t)b * 16384 + idx];
  }
  __syncthreads();
  int s2 = tid & 31, part = tid >> 5;
  float m = -1e30f;
  for (int l = part * 64; l < part * 64 + 64; ++l)
    m = fmaxf(m, wl[s2 * 512 + (l ^ s2)]);
  pm[s2][part] = m;
  __syncthreads();
  float M = pm[s2][0];
  #pragma unroll
  for (int j = 1; j < 8; ++j) M = fmaxf(M, pm[s2][j]);
  float sum = 0.0f;
  for (int l = part * 64; l < part * 64 + 64; ++l)
    sum += __expf(wl[s2 * 512 + (l ^ s2)] - M);
  ps[s2][part] = sum;
  __syncthreads();
  if (part == 0){
    float Lt = ps[s2][0];
    #pragma unroll
    for (int j = 1; j < 8; ++j) Lt += ps[s2][j];
    Mf[s2] = M;
    invf[s2] = __builtin_amdgcn_rcpf(Lt);
  }
  __syncthreads();
  for (int l = part * 64; l < part * 64 + 64; ++l){
    int a = s2 * 512 + (l ^ s2);
    wl[a] = __expf(wl[a] - Mf[s2]) * invf[s2];
  }
  __syncthreads();
  int d = dt * 32 + (tid & 31);
  int grp = tid >> 5;
  int r0 = grp * 4, r1 = r0 + 1, r2 = r0 + 2, r3 = r0 + 3;
  float acc0 = 0, acc1 = 0, acc2 = 0, acc3 = 0;
  const unsigned short* ebase = encb + (size_t)b * 262144 + d;   // 512*512
  #pragma unroll 8
  for (int l = 0; l < 512; ++l){
    float e = bf2f(ebase[(size_t)l * 512]);
    acc0 = fmaf(wl[r0 * 512 + (l ^ r0)], e, acc0);
    acc1 = fmaf(wl[r1 * 512 + (l ^ r1)], e, acc1);
    acc2 = fmaf(wl[r2 * 512 + (l ^ r2)], e, acc2);
    acc3 = fmaf(wl[r3 * 512 + (l ^ r3)], e, acc3);
  }
  size_t obase = (size_t)(b * 32 + r0) * 512 + d;
  ctx[obase]        = f2bf(acc0);
  ctx[obase + 512]  = f2bf(acc1);
  ctx[obase + 1024] = f2bf(acc2);
  ctx[obase + 1536] = f2bf(acc3);
}

// ---------------- main GEMM (128x256 tile, wave 64x64, A-dbuf + B-3buf, vmcnt(2)):
//   out[m][v] = ctx[m] . Wc[v] + logh[m&31][v]
//   epilogue: per-wave LDS transpose -> global_store_dwordx4 (4x fewer store instrs)
extern "C" __global__ void __launch_bounds__(512, 4)
k_gemm_main(const unsigned short* __restrict__ Abf, const unsigned short* __restrict__ Wc,
            const float* __restrict__ logh, float* __restrict__ out){
  __shared__ char smem[65536];
  unsigned short* As0 = (unsigned short*)smem;            // 2 x 128*32 bf16 = 16 KB
  unsigned short* Bs0 = (unsigned short*)(smem + 16384);  // 3 x 256*32 bf16 = 48 KB
  float* ep = (float*)smem;                               // epilogue scratch (reused)
  int orig = blockIdx.x;
  int wg = (orig & 7) * 125 + (orig >> 3);
  int bm = wg & 7, bn = wg >> 3;            // bm<8, bn<125
  int tid = threadIdx.x, wid = tid >> 6, lane = tid & 63;
  int fr = lane & 15, fq = lane >> 4;
  int wm = wid >> 2, wn = wid & 3;          // 2x4 waves; wave tile 64x64
  int abase = bm * 128, bbase = bn * 256;
  int srow = lane >> 2;
  int scol = ((lane & 3) ^ ((lane >> 3) & 3)) * 8;
  const unsigned short* aS0 = Abf + (size_t)(abase + wid * 16 + srow) * 512 + scol;
  const unsigned short* bS0 = Wc  + (size_t)(bbase + wid * 32 + srow) * 512 + scol;
  const unsigned short* bS1 = bS0 + (size_t)16 * 512;
  int swzfq = (fq ^ ((fr >> 1) & 3)) * 8;

  f32x4 acc[4][4];
  #pragma unroll
  for (int i = 0; i < 4; ++i)
    #pragma unroll
    for (int jj = 0; jj < 4; ++jj) acc[i][jj] = (f32x4)0.0f;

#define STAGE_A(buf, kk) gl_lds16(aS0 + (kk), As0 + (buf) * 4096 + wid * 512)
#define STAGE_B(buf, kk) do { \
    gl_lds16(bS0 + (kk), Bs0 + (buf) * 8192 + wid * 1024); \
    gl_lds16(bS1 + (kk), Bs0 + (buf) * 8192 + wid * 1024 + 512); \
  } while (0)

  STAGE_A(0, 0);
  STAGE_B(0, 0);
  STAGE_B(1, 32);
  asm volatile("s_waitcnt vmcnt(2)" ::: "memory");   // A0,B0 landed; B1 flying
  __builtin_amdgcn_s_barrier();
  __builtin_amdgcn_sched_barrier(0);

  #pragma unroll
  for (int t = 0; t < 16; ++t){
    const int ca = t & 1, cb = t % 3;
    short8 a[4], b[4];
    if (t < 15) STAGE_A(ca ^ 1, (size_t)(t + 1) * 32);
    #pragma unroll
    for (int nf = 0; nf < 4; ++nf)
      b[nf] = *(const short8*)&Bs0[cb * 8192 + (wn * 64 + nf * 16 + fr) * 32 + swzfq];
    #pragma unroll
    for (int mf = 0; mf < 2; ++mf)
      a[mf] = *(const short8*)&As0[ca * 4096 + (wm * 64 + mf * 16 + fr) * 32 + swzfq];
    __builtin_amdgcn_s_setprio(1);
    #pragma unroll
    for (int mf = 0; mf < 2; ++mf)
      #pragma unroll
      for (int nf = 0; nf < 4; ++nf)
        acc[mf][nf] = __builtin_amdgcn_mfma_f32_16x16x32_bf16(a[mf], b[nf], acc[mf][nf], 0, 0, 0);
    __builtin_amdgcn_s_setprio(0);
    if (t < 14) STAGE_B((t + 2) % 3, (size_t)(t + 2) * 32);
    #pragma unroll
    for (int mf = 2; mf < 4; ++mf)
      a[mf] = *(const short8*)&As0[ca * 4096 + (wm * 64 + mf * 16 + fr) * 32 + swzfq];
    __builtin_amdgcn_s_setprio(1);
    #pragma unroll
    for (int mf = 2; mf < 4; ++mf)
      #pragma unroll
      for (int nf = 0; nf < 4; ++nf)
        acc[mf][nf] = __builtin_amdgcn_mfma_f32_16x16x32_bf16(a[mf], b[nf], acc[mf][nf], 0, 0, 0);
    __builtin_amdgcn_s_setprio(0);
    if (t < 14)       asm volatile("s_waitcnt vmcnt(2)" ::: "memory");
    else if (t == 14) asm volatile("s_waitcnt vmcnt(0)" ::: "memory");
    if (t < 15){
      __builtin_amdgcn_s_barrier();
      __builtin_amdgcn_sched_barrier(0);
    }
  }
#undef STAGE_A
#undef STAGE_B

  // ---- epilogue: add logh, transpose via per-wave LDS, store dwordx4 ----
  __syncthreads();                          // all waves done reading As0/Bs0
  float* myep = ep + wid * 1088;            // 16 rows x 68 f32 (pad) = 4352 B/wave
  int colb = bn * 256 + wn * 64;
  #pragma unroll
  for (int mf = 0; mf < 4; ++mf){
    // write phase: final = acc + logh  ->  ep[row16][col64]
    #pragma unroll
    for (int nf = 0; nf < 4; ++nf){
      int col = colb + nf * 16 + fr;
      #pragma unroll
      for (int jj = 0; jj < 4; ++jj){
        int lrow = (mf * 16 + fq * 4 + jj) & 31;   // logh row (bm*128,wm*64 are mult of 32)
        myep[(fq * 4 + jj) * 68 + nf * 16 + fr] = acc[mf][nf][jj] + logh[(size_t)lrow * VOC_ + col];
      }
    }
    asm volatile("s_waitcnt lgkmcnt(0)" ::: "memory");
    __builtin_amdgcn_sched_barrier(0);
    // read phase: lane holds 4 consecutive cols -> dwordx4 stores (256B/row/instr)
    int rrow = lane >> 4;                    // 0..3
    int rcol = (lane & 15) * 4;              // 0..60
    #pragma unroll
    for (int cch = 0; cch < 4; ++cch){
      f32x4 v = *(const f32x4*)&myep[(rrow + 4 * cch) * 68 + rcol];
      int gr = bm * 128 + wm * 64 + mf * 16 + rrow + 4 * cch;
      *(f32x4*)&out[(size_t)gr * VOC_ + colb + rcol] = v;
    }
    asm volatile("s_waitcnt lgkmcnt(0)" ::: "memory");
    __builtin_amdgcn_sched_barrier(0);
  }
}

extern "C" void kernel_launch(void* const* d_in, const int* in_sizes, int n_in,
                              void* d_out, int out_size, void* d_ws, size_t ws_size,
                              hipStream_t stream){
  const float* enc = (const float*)d_in[0];
  // d_in[1] = target_seq (unused: only its shape matters in the reference)
  const float* pos = (const float*)d_in[2];
  const float* dW  = (const float*)d_in[3];
  const float* db  = (const float*)d_in[4];
  const float* eW  = (const float*)d_in[5];
  const float* eb  = (const float*)d_in[6];
  const float* vW  = (const float*)d_in[7];
  // d_in[8] = attn_score_b: constant over l, cancels exactly in softmax
  const float* hW  = (const float*)d_in[9];
  const float* hb  = (const float*)d_in[10];
  const float* fcW = (const float*)d_in[11];
  const float* fcb = (const float*)d_in[12];
  float* out = (float*)d_out;

  char* w = (char*)d_ws;
  unsigned short* Wc_bf   = (unsigned short*)(w);               // 32,768,000 B
  unsigned short* enc_bf  = (unsigned short*)(w + 32768000);    // 16,777,216 B
  unsigned short* encp_bf = (unsigned short*)(w + 49545216);    //  8,388,608 B
  unsigned short* ctx     = (unsigned short*)(w + 57933824);    //  1,048,576 B
  float*          logh    = (float*)(w + 58982400);             //  4,096,000 B
  float*          dq      = (float*)(w + 63078400);             //     32,768 B
  unsigned short* hbf     = (unsigned short*)(w + 63111168);    //     32,768 B
  unsigned short* encW_bf = (unsigned short*)(w + 63143936);    //    262,144 B
  float*          scoreT  = (float*)(w + 63406080);             //  2,097,152 B (total ~65.5 MB)

  k_prep<<<dim3(8416), dim3(256), 0, stream>>>(enc, enc_bf, eW, encW_bf,
                                               pos, dW, db, hW, hb, dq, hbf);
  k_gemm_encp<<<dim3(256), dim3(256), 0, stream>>>(enc_bf, encW_bf, eb, encp_bf);
  k_mid<<<dim3(1274), dim3(512), 0, stream>>>(fcW, hbf, fcb, Wc_bf, logh,
                                              encp_bf, dq, vW, scoreT);
  k_ctx<<<dim3(512), dim3(256), 0, stream>>>(enc_bf, scoreT, ctx);
  k_gemm_main<<<dim3(1000), dim3(512), 0, stream>>>(ctx, Wc_bf, logh, out);
}

// Round 20
// 184.565 us; speedup vs baseline: 1.0314x; 1.0081x over previous
//
#include <hip/hip_runtime.h>
#include <hip/hip_bf16.h>
#include <stdint.h>

typedef __attribute__((ext_vector_type(4))) float f32x4;
typedef __attribute__((ext_vector_type(8))) short short8;

#define B_   32
#define L_   512
#define DE_  512
#define S_   32
#define ED_  128
#define AD_  256
#define HD_  512
#define VOC_ 32000
#define M_   1024
#define SCL_ 2.885390081777927f   // 2*log2(e): tanh(z) = 1 - 2/(2^(SCL*z)+1)

__device__ __forceinline__ unsigned short f2bf(float f){
  union { float f; unsigned int u; } v; v.f = f;
  unsigned int u = v.u;
  unsigned int r = (u + 0x7FFFu + ((u >> 16) & 1u)) >> 16;  // RNE
  return (unsigned short)r;
}

__device__ __forceinline__ float bf2f(unsigned short u){
  union { unsigned int u; float f; } v; v.u = ((unsigned int)u) << 16;
  return v.f;
}

// raw v_exp_f32 (2^x) — avoids libm exp2f's fixup sequence
__device__ __forceinline__ float hw_exp2(float x){
#if __has_builtin(__builtin_amdgcn_exp2f)
  return __builtin_amdgcn_exp2f(x);
#else
  float r;
  asm("v_exp_f32 %0, %1" : "=v"(r) : "v"(x));
  return r;
#endif
}

__device__ __forceinline__ void gl_lds16(const void* g, void* l){
  __builtin_amdgcn_global_load_lds(
      (const __attribute__((address_space(1))) unsigned int*)g,
      (__attribute__((address_space(3))) unsigned int*)l, 16, 0, 0);
}

// per-row score partial: 4 independent exp2/rcp/fma chains over 16 elements
__device__ __forceinline__ float row_score(short8 ea, short8 eb,
                                           const f32x4* dqv, const f32x4* vv, float Vg){
  const unsigned int* ua = (const unsigned int*)&ea;
  const unsigned int* ub = (const unsigned int*)&eb;
  float a0 = 0, a1 = 0, a2 = 0, a3 = 0;
  #pragma unroll
  for (int j = 0; j < 2; ++j){
    unsigned int w0 = ua[j * 2], w1 = ua[j * 2 + 1];
    float t0 = hw_exp2(__uint_as_float(w0 << 16)         + dqv[j][0]);
    float t1 = hw_exp2(__uint_as_float(w0 & 0xffff0000u) + dqv[j][1]);
    float t2 = hw_exp2(__uint_as_float(w1 << 16)         + dqv[j][2]);
    float t3 = hw_exp2(__uint_as_float(w1 & 0xffff0000u) + dqv[j][3]);
    a0 = fmaf(vv[j][0], __builtin_amdgcn_rcpf(t0 + 1.0f), a0);
    a1 = fmaf(vv[j][1], __builtin_amdgcn_rcpf(t1 + 1.0f), a1);
    a2 = fmaf(vv[j][2], __builtin_amdgcn_rcpf(t2 + 1.0f), a2);
    a3 = fmaf(vv[j][3], __builtin_amdgcn_rcpf(t3 + 1.0f), a3);
  }
  #pragma unroll
  for (int j = 0; j < 2; ++j){
    unsigned int w0 = ub[j * 2], w1 = ub[j * 2 + 1];
    float t0 = hw_exp2(__uint_as_float(w0 << 16)         + dqv[2 + j][0]);
    float t1 = hw_exp2(__uint_as_float(w0 & 0xffff0000u) + dqv[2 + j][1]);
    float t2 = hw_exp2(__uint_as_float(w1 << 16)         + dqv[2 + j][2]);
    float t3 = hw_exp2(__uint_as_float(w1 & 0xffff0000u) + dqv[2 + j][3]);
    a0 = fmaf(vv[2 + j][0], __builtin_amdgcn_rcpf(t0 + 1.0f), a0);
    a1 = fmaf(vv[2 + j][1], __builtin_amdgcn_rcpf(t1 + 1.0f), a1);
    a2 = fmaf(vv[2 + j][2], __builtin_amdgcn_rcpf(t2 + 1.0f), a2);
    a3 = fmaf(vv[2 + j][3], __builtin_amdgcn_rcpf(t3 + 1.0f), a3);
  }
  return fmaf(-2.0f, (a0 + a1) + (a2 + a3), Vg);
}

// ---------------- fused prologue: enc cvt (8192 blk) + eW cvt (128 blk) + small (96 blk) ----
extern "C" __global__ void __launch_bounds__(256)
k_prep(const float* __restrict__ enc, unsigned short* __restrict__ enc_bf,
       const float* __restrict__ eW, unsigned short* __restrict__ encW_bf,
       const float* __restrict__ pos,
       const float* __restrict__ dW, const float* __restrict__ db,
       const float* __restrict__ hW, const float* __restrict__ hb,
       float* __restrict__ dq, unsigned short* __restrict__ hbf){
  int blk = blockIdx.x, tid = threadIdx.x;
  if (blk < 8192){                       // enc: 2,097,152 f32x4, one per thread
    int i = blk * 256 + tid;
    f32x4 v = ((const f32x4*)enc)[i];
    ushort4 o;
    o.x = f2bf(v[0]); o.y = f2bf(v[1]); o.z = f2bf(v[2]); o.w = f2bf(v[3]);
    ((ushort4*)enc_bf)[i] = o;
  } else if (blk < 8320){                // eW: 32,768 f32x4
    int i = (blk - 8192) * 256 + tid;
    f32x4 v = ((const f32x4*)eW)[i];
    ushort4 o;
    o.x = f2bf(v[0]); o.y = f2bf(v[1]); o.z = f2bf(v[2]); o.w = f2bf(v[3]);
    ((ushort4*)encW_bf)[i] = o;
  } else {                               // dq [32][256] f32 (pre-scaled), hidden bf16
    int t = (blk - 8320) * 256 + tid;
    if (t < S_ * AD_){
      int s = t >> 8, a = t & 255;
      const float* p = pos + s * ED_;
      const float* wrow = dW + a * ED_;
      float acc = db[a];
      #pragma unroll 4
      for (int e = 0; e < ED_; ++e) acc += p[e] * wrow[e];
      dq[t] = SCL_ * acc;                // pre-scale for exp2-based tanh
    } else if (t < S_ * AD_ + S_ * HD_){
      int u = t - S_ * AD_;
      int s = u >> 9, h = u & 511;
      const float* p = pos + s * ED_;
      const float* wrow = hW + h * ED_;
      float acc = hb[h];
      #pragma unroll 4
      for (int e = 0; e < ED_; ++e) acc += p[e] * wrow[e];
      hbf[u] = f2bf(acc);
    }
  }
}

// ---------------- enc_proj GEMM (128x128 tile, 2-phase dbuf, swizzled LDS):
//   [16384x512]bf16 @ [256x512]bf16^T -> bf16( SCL*(acc+bias) )  [feeds score only]
extern "C" __global__ void __launch_bounds__(256, 4)
k_gemm_encp(const unsigned short* __restrict__ A, const unsigned short* __restrict__ Bt,
            const float* __restrict__ bias, unsigned short* __restrict__ C){
  __shared__ unsigned short As[2][128 * 32];
  __shared__ unsigned short Bs[2][128 * 32];
  int bm = blockIdx.x >> 1, bn = blockIdx.x & 1;
  int tid = threadIdx.x, wid = tid >> 6, lane = tid & 63;
  int fr = lane & 15, fq = lane >> 4;
  int wm = wid >> 1, wn = wid & 1;       // 2x2 waves; wave tile 64x64
  int srow = lane >> 2;
  int scol = ((lane & 3) ^ ((lane >> 3) & 3)) * 8;   // pre-swizzled source col
  int c0 = wid * 2;
  const unsigned short* aS0 = A  + (size_t)(bm * 128 + c0 * 16 + srow) * 512 + scol;
  const unsigned short* aS1 = aS0 + (size_t)16 * 512;
  const unsigned short* bS0 = Bt + (size_t)(bn * 128 + c0 * 16 + srow) * 512 + scol;
  const unsigned short* bS1 = bS0 + (size_t)16 * 512;
  int swzfq = (fq ^ ((fr >> 1) & 3)) * 8;

  f32x4 acc[4][4];
  #pragma unroll
  for (int i = 0; i < 4; ++i)
    #pragma unroll
    for (int j = 0; j < 4; ++j) acc[i][j] = (f32x4)0.0f;

#define STAGE_E(buf, kk) do { \
    gl_lds16(aS0 + (kk), &As[buf][c0 * 512]); \
    gl_lds16(aS1 + (kk), &As[buf][c0 * 512 + 512]); \
    gl_lds16(bS0 + (kk), &Bs[buf][c0 * 512]); \
    gl_lds16(bS1 + (kk), &Bs[buf][c0 * 512 + 512]); \
  } while (0)

  STAGE_E(0, 0);
  __syncthreads();

  int cur = 0;
  for (int t = 0; t < 16; ++t){
    if (t < 15) STAGE_E(cur ^ 1, (size_t)(t + 1) * 32);
    short8 a[4], b[4];
    #pragma unroll
    for (int mf = 0; mf < 4; ++mf) a[mf] = *(const short8*)&As[cur][(wm * 64 + mf * 16 + fr) * 32 + swzfq];
    #pragma unroll
    for (int nf = 0; nf < 4; ++nf) b[nf] = *(const short8*)&Bs[cur][(wn * 64 + nf * 16 + fr) * 32 + swzfq];
    #pragma unroll
    for (int mf = 0; mf < 4; ++mf)
      #pragma unroll
      for (int nf = 0; nf < 4; ++nf)
        acc[mf][nf] = __builtin_amdgcn_mfma_f32_16x16x32_bf16(a[mf], b[nf], acc[mf][nf], 0, 0, 0);
    __syncthreads();
    cur ^= 1;
  }
#undef STAGE_E

  #pragma unroll
  for (int mf = 0; mf < 4; ++mf){
    int row = bm * 128 + wm * 64 + mf * 16 + fq * 4;
    #pragma unroll
    for (int nf = 0; nf < 4; ++nf){
      int col = bn * 128 + wn * 64 + nf * 16 + fr;
      float bv = bias[col];
      #pragma unroll
      for (int j = 0; j < 4; ++j)
        C[(size_t)(row + j) * 256 + col] = f2bf(SCL_ * (acc[mf][nf][j] + bv));
    }
  }
}

// ---------------- fused middle (512-thread blocks):
//   wprep (blocks 0-249, 128 fcW rows each) || attn scores (blocks 250-1273)
// eL / pp are SEPARATE __shared__ objects (no-alias -> ds_reads pipeline across pp writes)
extern "C" __global__ void __launch_bounds__(512)
k_mid(const float* __restrict__ fcW, const unsigned short* __restrict__ hbf,
      const float* __restrict__ fcb, unsigned short* __restrict__ Wc,
      float* __restrict__ logh,
      const unsigned short* __restrict__ encp, const float* __restrict__ dq,
      const float* __restrict__ vW, float* __restrict__ scoreT){
  __shared__ unsigned short eL[16 * 256];   // 8 KB
  __shared__ float pp[16 * 512];            // 32 KB
  int blk = blockIdx.x, tid = threadIdx.x;
  if (blk < 250){
    // ---------------- wprep: Wc_bf convert + logh for 128 fcW rows ----------------
    int base = blk * 128;
    int wid = tid >> 6, lane = tid & 63;
    int fr = lane & 15, fq = lane >> 4;
    // part 1: convert upper half (cols 512:1024) of 128 rows: 16384 f32x4
    #pragma unroll 8
    for (int i = 0; i < 32; ++i){
      int idx = i * 512 + tid;
      int row = idx >> 7, c4 = idx & 127;
      f32x4 v = *(const f32x4*)&fcW[(size_t)(base + row) * 1024 + 512 + c4 * 4];
      ushort4 o;
      o.x = f2bf(v[0]); o.y = f2bf(v[1]); o.z = f2bf(v[2]); o.w = f2bf(v[3]);
      *(ushort4*)&Wc[(size_t)(base + row) * 512 + c4 * 4] = o;
    }
    // part 2: logh for 128 cols (8 waves x 16 cols), LDS-free bf16 MFMA vs hbf
    int col = base + wid * 16 + fr;
    const float* brow = fcW + (size_t)col * 1024;
    f32x4 acc0 = (f32x4)0.0f, acc1 = (f32x4)0.0f;
    #pragma unroll 4
    for (int k0 = 0; k0 < 512; k0 += 32){
      int ko = k0 + fq * 8;
      f32x4 b0 = *(const f32x4*)(brow + ko);
      f32x4 b1 = *(const f32x4*)(brow + ko + 4);
      short8 bfr;
      bfr[0] = (short)f2bf(b0[0]); bfr[1] = (short)f2bf(b0[1]);
      bfr[2] = (short)f2bf(b0[2]); bfr[3] = (short)f2bf(b0[3]);
      bfr[4] = (short)f2bf(b1[0]); bfr[5] = (short)f2bf(b1[1]);
      bfr[6] = (short)f2bf(b1[2]); bfr[7] = (short)f2bf(b1[3]);
      short8 a0 = *(const short8*)&hbf[(size_t)fr * 512 + ko];
      short8 a1 = *(const short8*)&hbf[(size_t)(16 + fr) * 512 + ko];
      acc0 = __builtin_amdgcn_mfma_f32_16x16x32_bf16(a0, bfr, acc0, 0, 0, 0);
      acc1 = __builtin_amdgcn_mfma_f32_16x16x32_bf16(a1, bfr, acc1, 0, 0, 0);
    }
    float bv = fcb[col];
    #pragma unroll
    for (int j = 0; j < 4; ++j){
      logh[(size_t)(fq * 4 + j) * VOC_ + col]      = acc0[j] + bv;
      logh[(size_t)(16 + fq * 4 + j) * VOC_ + col] = acc1[j] + bv;
    }
  } else {
    // ---------------- attn scores: block (b, c) owns 16 l-rows, all 32 s ----------
    // LDS slot layout per row: slot sl<16 holds global 16B-group 2*sl, else 2*(sl-16)+1
    // -> thread g reads slots g and g+16 (banks 4g%32: 2-way, free).
    int blk2 = blk - 250;                             // 1024 = 32 b x 32 chunks
    int b = blk2 >> 5, c = blk2 & 31;
    int w = tid >> 6, lane = tid & 63;
    {
      int sl = lane & 31;
      int row = 2 * w + (lane >> 5);
      int srcgrp = (sl < 16) ? (2 * sl) : (2 * (sl - 16) + 1);
      gl_lds16(encp + (size_t)(b * 512 + c * 16 + row) * 256 + srcgrp * 8,
               &eL[w * 512]);                         // wave-uniform base, lane*16B
    }
    int s = tid >> 4, g = tid & 15;                   // 32 s x 16 g
    f32x4 dqv[4], vv[4];
    #pragma unroll
    for (int k = 0; k < 4; ++k){
      dqv[k] = *(const f32x4*)&dq[s * 256 + g * 16 + k * 4];
      vv[k]  = *(const f32x4*)&vW[g * 16 + k * 4];
    }
    float Vg = 0.0f;
    #pragma unroll
    for (int k = 0; k < 4; ++k)
      Vg += (vv[k][0] + vv[k][1]) + (vv[k][2] + vv[k][3]);
    __syncthreads();   // eL ready
    // 2 rows per iteration: 8 independent chains; separate shared objects let the
    // scheduler hoist the 4 ds_read_b128 above/past the pp writes.
    #pragma unroll
    for (int l2 = 0; l2 < 8; ++l2){
      int l0 = l2 * 2, l1 = l2 * 2 + 1;
      short8 ea0 = *(const short8*)&eL[l0 * 256 + g * 8];
      short8 eb0 = *(const short8*)&eL[l0 * 256 + (g + 16) * 8];
      short8 ea1 = *(const short8*)&eL[l1 * 256 + g * 8];
      short8 eb1 = *(const short8*)&eL[l1 * 256 + (g + 16) * 8];
      float r0 = row_score(ea0, eb0, dqv, vv, Vg);
      float r1 = row_score(ea1, eb1, dqv, vv, Vg);
      pp[l0 * 512 + tid] = r0;
      pp[l1 * 512 + tid] = r1;
    }
    __syncthreads();
    // reduce 16 g-partials per (l,s); write scoreT [b][l][s]
    {
      int l = tid >> 5, ss = tid & 31;
      const float* p = &pp[l * 512 + ss * 16];
      f32x4 x0 = *(const f32x4*)(p);
      f32x4 x1 = *(const f32x4*)(p + 4);
      f32x4 x2 = *(const f32x4*)(p + 8);
      f32x4 x3 = *(const f32x4*)(p + 12);
      float sum = ((x0[0] + x0[1]) + (x0[2] + x0[3])) + ((x1[0] + x1[1]) + (x1[2] + x1[3]))
                + ((x2[0] + x2[1]) + (x2[2] + x2[3])) + ((x3[0] + x3[1]) + (x3[2] + x3[3]));
      scoreT[((size_t)b * 512 + c * 16 + l) * 32 + ss] = sum;
    }
  }
}

// ---------------- context (softmax folded in):
//   stage scoreT[b] -> LDS (XOR-swizzled), per-s softmax in place, then
//   ctx[b*32+s][d] = sum_l w[b,s,l] * enc_bf[b,l,d] -> bf16
extern "C" __global__ void __launch_bounds__(256)
k_ctx(const unsigned short* __restrict__ encb, const float* __restrict__ scoreT,
      unsigned short* __restrict__ ctx){
  __shared__ float wl[32 * 512];        // 64 KB, [s][l ^ s] swizzle
  __shared__ float pm[32][8], ps[32][8];
  __shared__ float Mf[32], invf[32];
  int b = blockIdx.x >> 4, dt = blockIdx.x & 15;
  int tid = threadIdx.x;
  for (int idx = tid; idx < 16384; idx += 256){
    int l = idx >> 5, s = idx & 31;
    wl[s * 512 + (l ^ s)] = scoreT[(size_t)b * 16384 + idx];
  }
  __syncthreads();
  int s2 = tid & 31, part = tid >> 5;
  float m = -1e30f;
  for (int l = part * 64; l < part * 64 + 64; ++l)
    m = fmaxf(m, wl[s2 * 512 + (l ^ s2)]);
  pm[s2][part] = m;
  __syncthreads();
  float M = pm[s2][0];
  #pragma unroll
  for (int j = 1; j < 8; ++j) M = fmaxf(M, pm[s2][j]);
  float sum = 0.0f;
  for (int l = part * 64; l < part * 64 + 64; ++l)
    sum += __expf(wl[s2 * 512 + (l ^ s2)] - M);
  ps[s2][part] = sum;
  __syncthreads();
  if (part == 0){
    float Lt = ps[s2][0];
    #pragma unroll
    for (int j = 1; j < 8; ++j) Lt += ps[s2][j];
    Mf[s2] = M;
    invf[s2] = __builtin_amdgcn_rcpf(Lt);
  }
  __syncthreads();
  for (int l = part * 64; l < part * 64 + 64; ++l){
    int a = s2 * 512 + (l ^ s2);
    wl[a] = __expf(wl[a] - Mf[s2]) * invf[s2];
  }
  __syncthreads();
  int d = dt * 32 + (tid & 31);
  int grp = tid >> 5;
  int r0 = grp * 4, r1 = r0 + 1, r2 = r0 + 2, r3 = r0 + 3;
  float acc0 = 0, acc1 = 0, acc2 = 0, acc3 = 0;
  const unsigned short* ebase = encb + (size_t)b * 262144 + d;   // 512*512
  #pragma unroll 8
  for (int l = 0; l < 512; ++l){
    float e = bf2f(ebase[(size_t)l * 512]);
    acc0 = fmaf(wl[r0 * 512 + (l ^ r0)], e, acc0);
    acc1 = fmaf(wl[r1 * 512 + (l ^ r1)], e, acc1);
    acc2 = fmaf(wl[r2 * 512 + (l ^ r2)], e, acc2);
    acc3 = fmaf(wl[r3 * 512 + (l ^ r3)], e, acc3);
  }
  size_t obase = (size_t)(b * 32 + r0) * 512 + d;
  ctx[obase]        = f2bf(acc0);
  ctx[obase + 512]  = f2bf(acc1);
  ctx[obase + 1024] = f2bf(acc2);
  ctx[obase + 1536] = f2bf(acc3);
}

// ---------------- main GEMM (128x256 tile, wave 64x64, A-dbuf + B-3buf, vmcnt(2)):
//   out[m][v] = ctx[m] . Wc[v] + logh[m&31][v]
//   epilogue: per-wave LDS transpose -> global_store_dwordx4 (4x fewer store instrs)
extern "C" __global__ void __launch_bounds__(512, 4)
k_gemm_main(const unsigned short* __restrict__ Abf, const unsigned short* __restrict__ Wc,
            const float* __restrict__ logh, float* __restrict__ out){
  __shared__ char smem[65536];
  unsigned short* As0 = (unsigned short*)smem;            // 2 x 128*32 bf16 = 16 KB
  unsigned short* Bs0 = (unsigned short*)(smem + 16384);  // 3 x 256*32 bf16 = 48 KB
  float* ep = (float*)smem;                               // epilogue scratch (reused)
  int orig = blockIdx.x;
  int wg = (orig & 7) * 125 + (orig >> 3);
  int bm = wg & 7, bn = wg >> 3;            // bm<8, bn<125
  int tid = threadIdx.x, wid = tid >> 6, lane = tid & 63;
  int fr = lane & 15, fq = lane >> 4;
  int wm = wid >> 2, wn = wid & 3;          // 2x4 waves; wave tile 64x64
  int abase = bm * 128, bbase = bn * 256;
  int srow = lane >> 2;
  int scol = ((lane & 3) ^ ((lane >> 3) & 3)) * 8;
  const unsigned short* aS0 = Abf + (size_t)(abase + wid * 16 + srow) * 512 + scol;
  const unsigned short* bS0 = Wc  + (size_t)(bbase + wid * 32 + srow) * 512 + scol;
  const unsigned short* bS1 = bS0 + (size_t)16 * 512;
  int swzfq = (fq ^ ((fr >> 1) & 3)) * 8;

  f32x4 acc[4][4];
  #pragma unroll
  for (int i = 0; i < 4; ++i)
    #pragma unroll
    for (int jj = 0; jj < 4; ++jj) acc[i][jj] = (f32x4)0.0f;

#define STAGE_A(buf, kk) gl_lds16(aS0 + (kk), As0 + (buf) * 4096 + wid * 512)
#define STAGE_B(buf, kk) do { \
    gl_lds16(bS0 + (kk), Bs0 + (buf) * 8192 + wid * 1024); \
    gl_lds16(bS1 + (kk), Bs0 + (buf) * 8192 + wid * 1024 + 512); \
  } while (0)

  STAGE_A(0, 0);
  STAGE_B(0, 0);
  STAGE_B(1, 32);
  asm volatile("s_waitcnt vmcnt(2)" ::: "memory");   // A0,B0 landed; B1 flying
  __builtin_amdgcn_s_barrier();
  __builtin_amdgcn_sched_barrier(0);

  #pragma unroll
  for (int t = 0; t < 16; ++t){
    const int ca = t & 1, cb = t % 3;
    short8 a[4], b[4];
    if (t < 15) STAGE_A(ca ^ 1, (size_t)(t + 1) * 32);
    #pragma unroll
    for (int nf = 0; nf < 4; ++nf)
      b[nf] = *(const short8*)&Bs0[cb * 8192 + (wn * 64 + nf * 16 + fr) * 32 + swzfq];
    #pragma unroll
    for (int mf = 0; mf < 2; ++mf)
      a[mf] = *(const short8*)&As0[ca * 4096 + (wm * 64 + mf * 16 + fr) * 32 + swzfq];
    __builtin_amdgcn_s_setprio(1);
    #pragma unroll
    for (int mf = 0; mf < 2; ++mf)
      #pragma unroll
      for (int nf = 0; nf < 4; ++nf)
        acc[mf][nf] = __builtin_amdgcn_mfma_f32_16x16x32_bf16(a[mf], b[nf], acc[mf][nf], 0, 0, 0);
    __builtin_amdgcn_s_setprio(0);
    if (t < 14) STAGE_B((t + 2) % 3, (size_t)(t + 2) * 32);
    #pragma unroll
    for (int mf = 2; mf < 4; ++mf)
      a[mf] = *(const short8*)&As0[ca * 4096 + (wm * 64 + mf * 16 + fr) * 32 + swzfq];
    __builtin_amdgcn_s_setprio(1);
    #pragma unroll
    for (int mf = 2; mf < 4; ++mf)
      #pragma unroll
      for (int nf = 0; nf < 4; ++nf)
        acc[mf][nf] = __builtin_amdgcn_mfma_f32_16x16x32_bf16(a[mf], b[nf], acc[mf][nf], 0, 0, 0);
    __builtin_amdgcn_s_setprio(0);
    if (t < 14)       asm volatile("s_waitcnt vmcnt(2)" ::: "memory");
    else if (t == 14) asm volatile("s_waitcnt vmcnt(0)" ::: "memory");
    if (t < 15){
      __builtin_amdgcn_s_barrier();
      __builtin_amdgcn_sched_barrier(0);
    }
  }
#undef STAGE_A
#undef STAGE_B

  // ---- epilogue: add logh, transpose via per-wave LDS, store dwordx4 ----
  __syncthreads();                          // all waves done reading As0/Bs0
  float* myep = ep + wid * 1088;            // 16 rows x 68 f32 (pad) = 4352 B/wave
  int colb = bn * 256 + wn * 64;
  #pragma unroll
  for (int mf = 0; mf < 4; ++mf){
    // write phase: final = acc + logh  ->  ep[row16][col64]
    #pragma unroll
    for (int nf = 0; nf < 4; ++nf){
      int col = colb + nf * 16 + fr;
      #pragma unroll
      for (int jj = 0; jj < 4; ++jj){
        int lrow = (mf * 16 + fq * 4 + jj) & 31;   // logh row (bm*128,wm*64 are mult of 32)
        myep[(fq * 4 + jj) * 68 + nf * 16 + fr] = acc[mf][nf][jj] + logh[(size_t)lrow * VOC_ + col];
      }
    }
    asm volatile("s_waitcnt lgkmcnt(0)" ::: "memory");
    __builtin_amdgcn_sched_barrier(0);
    // read phase: lane holds 4 consecutive cols -> dwordx4 stores (256B/row/instr)
    int rrow = lane >> 4;                    // 0..3
    int rcol = (lane & 15) * 4;              // 0..60
    #pragma unroll
    for (int cch = 0; cch < 4; ++cch){
      f32x4 v = *(const f32x4*)&myep[(rrow + 4 * cch) * 68 + rcol];
      int gr = bm * 128 + wm * 64 + mf * 16 + rrow + 4 * cch;
      *(f32x4*)&out[(size_t)gr * VOC_ + colb + rcol] = v;
    }
    asm volatile("s_waitcnt lgkmcnt(0)" ::: "memory");
    __builtin_amdgcn_sched_barrier(0);
  }
}

extern "C" void kernel_launch(void* const* d_in, const int* in_sizes, int n_in,
                              void* d_out, int out_size, void* d_ws, size_t ws_size,
                              hipStream_t stream){
  const float* enc = (const float*)d_in[0];
  // d_in[1] = target_seq (unused: only its shape matters in the reference)
  const float* pos = (const float*)d_in[2];
  const float* dW  = (const float*)d_in[3];
  const float* db  = (const float*)d_in[4];
  const float* eW  = (const float*)d_in[5];
  const float* eb  = (const float*)d_in[6];
  const float* vW  = (const float*)d_in[7];
  // d_in[8] = attn_score_b: constant over l, cancels exactly in softmax
  const float* hW  = (const float*)d_in[9];
  const float* hb  = (const float*)d_in[10];
  const float* fcW = (const float*)d_in[11];
  const float* fcb = (const float*)d_in[12];
  float* out = (float*)d_out;

  char* w = (char*)d_ws;
  unsigned short* Wc_bf   = (unsigned short*)(w);               // 32,768,000 B
  unsigned short* enc_bf  = (unsigned short*)(w + 32768000);    // 16,777,216 B
  unsigned short* encp_bf = (unsigned short*)(w + 49545216);    //  8,388,608 B
  unsigned short* ctx     = (unsigned short*)(w + 57933824);    //  1,048,576 B
  float*          logh    = (float*)(w + 58982400);             //  4,096,000 B
  float*          dq      = (float*)(w + 63078400);             //     32,768 B
  unsigned short* hbf     = (unsigned short*)(w + 63111168);    //     32,768 B
  unsigned short* encW_bf = (unsigned short*)(w + 63143936);    //    262,144 B
  float*          scoreT  = (float*)(w + 63406080);             //  2,097,152 B (total ~65.5 MB)

  k_prep<<<dim3(8416), dim3(256), 0, stream>>>(enc, enc_bf, eW, encW_bf,
                                               pos, dW, db, hW, hb, dq, hbf);
  k_gemm_encp<<<dim3(256), dim3(256), 0, stream>>>(enc_bf, encW_bf, eb, encp_bf);
  k_mid<<<dim3(1274), dim3(512), 0, stream>>>(fcW, hbf, fcb, Wc_bf, logh,
                                              encp_bf, dq, vW, scoreT);
  k_ctx<<<dim3(512), dim3(256), 0, stream>>>(enc_bf, scoreT, ctx);
  k_gemm_main<<<dim3(1000), dim3(512), 0, stream>>>(ctx, Wc_bf, logh, out);
}